// Round 10
// baseline (163.482 us; speedup 1.0000x reference)
//
#include <hip/hip_runtime.h>
#include <stdint.h>

#define SEQ 2048
#define QSCALE 0.1803368801111244f   // 0.125 * log2(e)
#define DEFER_THR 11.5f              // 8 nats in log2 units

typedef __attribute__((ext_vector_type(8))) short bf16x8;
typedef __attribute__((ext_vector_type(4))) short bf16x4;
typedef __attribute__((ext_vector_type(4))) float f32x4;
typedef __attribute__((ext_vector_type(16))) float f32x16;
typedef unsigned short u16;

__device__ __forceinline__ u16 f2bf(float f) {
  union { float f; uint32_t u; } v; v.f = f;
  uint32_t u = v.u;
  u += 0x7fffu + ((u >> 16) & 1u);   // RNE
  return (u16)(u >> 16);
}

__device__ __forceinline__ float bf2f(u16 b) {
  union { uint32_t u; float f; } v;
  v.u = ((uint32_t)b) << 16;
  return v.f;
}

__device__ __forceinline__ float fast_exp2(float x) {
#if __has_builtin(__builtin_amdgcn_exp2f)
  return __builtin_amdgcn_exp2f(x);   // v_exp_f32 (native base-2)
#else
  return exp2f(x);
#endif
}

__device__ __forceinline__ uint32_t cvtpk(float a, float b) {
  uint32_t r;
  asm("v_cvt_pk_bf16_f32 %0, %1, %2" : "=v"(r) : "v"(a), "v"(b));
  return r;
}

// exchange across lane<->lane^32 (R5-verified semantics, shfl-based):
// a' = (hi ? partner_b : a), b' = (hi ? b : partner_a)
__device__ __forceinline__ void swap_pair(uint32_t& a, uint32_t& b, int hi) {
  uint32_t ta = (uint32_t)__shfl_xor((int)a, 32);
  uint32_t tb = (uint32_t)__shfl_xor((int)b, 32);
  a = hi ? tb : a;
  b = hi ? b : ta;
}

__device__ __forceinline__ void gload_lds16(const u16* g, u16* l) {
  __builtin_amdgcn_global_load_lds((__attribute__((address_space(1))) void*)g,
                                   (__attribute__((address_space(3))) void*)l,
                                   16, 0, 0);
}

// ---------------- fused fp32 -> bf16 convert (all 5 tensors, 1 launch) -----
__global__ void cvt5_kernel(const float* __restrict__ x, const float* __restrict__ z,
                            const float* __restrict__ Wq, const float* __restrict__ Wkv,
                            const float* __restrict__ Wo,
                            u16* __restrict__ xb, u16* __restrict__ zb,
                            u16* __restrict__ wqb, u16* __restrict__ wkvb,
                            u16* __restrict__ wob) {
  const int X4 = 1048576, Z4 = 524288, W4 = 262144;
  const int total = X4 + Z4 + 3 * W4;
  int i = blockIdx.x * blockDim.x + threadIdx.x;
  const int stride = gridDim.x * blockDim.x;
  for (; i < total; i += stride) {
    const float* src; u16* dst; int j = i;
    if (j < X4)              { src = x;   dst = xb; }
    else if ((j -= X4) < Z4) { src = z;   dst = zb; }
    else if ((j -= Z4) < W4) { src = Wq;  dst = wqb; }
    else if ((j -= W4) < W4) { src = Wkv; dst = wkvb; }
    else       { j -= W4;      src = Wo;  dst = wob; }
    float4 v = ((const float4*)src)[j];
    bf16x4 o;
    o[0] = (short)f2bf(v.x); o[1] = (short)f2bf(v.y);
    o[2] = (short)f2bf(v.z); o[3] = (short)f2bf(v.w);
    ((bf16x4*)dst)[j] = o;
  }
}

// ---------------- C = scale * A(MxK) @ B(NxK)^T body, 128x128 tile, BK=64 --
// Staging swizzle: chunk c of row r stored at LDS position c, sourced from
// global chunk c^(r&7) (pre-swizzled source, linear LDS). Read: global chunk
// (ks*4+lg) of row (..+lq) is at position (ks*4+lg)^(lq&7).
__device__ __forceinline__ void gemm64_body(const u16* __restrict__ A,
                                            const u16* __restrict__ B,
                                            u16* __restrict__ C,
                                            int N, int K, float scale,
                                            int tm, int tn, u16* As, u16* Bs) {
  const int tid = threadIdx.x;
  const int wid = tid >> 6;
  const int lane = tid & 63;
  const int lg = lane >> 4, lq = lane & 15;
  const int wr = wid >> 1, wc = wid & 1;

  f32x4 acc[4][4];
#pragma unroll
  for (int m = 0; m < 4; m++)
#pragma unroll
    for (int n = 0; n < 4; n++)
#pragma unroll
      for (int e = 0; e < 4; e++) acc[m][n][e] = 0.f;

  const int r0 = tid >> 3;                 // 0..31
  const int c0 = tid & 7;                  // chunk 0..7
  const int sc = (c0 ^ (r0 & 7)) * 8;      // pre-swizzled source column
  const u16* gA = A + (size_t)(tm * 128 + r0) * K + sc;
  const u16* gB = B + (size_t)(tn * 128 + r0) * K + sc;
  u16* lA = As + wid * 512;                // linear LDS dest (512 u16/wave)
  u16* lB = Bs + wid * 512;

  for (int k0 = 0; k0 < K; k0 += 64) {
    __syncthreads();
#pragma unroll
    for (int i = 0; i < 4; i++) {
      // row-block i (32 rows x 64 cols = 2048 u16)
      gload_lds16(gA + k0 + (size_t)(32 * i) * K, lA + i * 2048);
      gload_lds16(gB + k0 + (size_t)(32 * i) * K, lB + i * 2048);
    }
    __syncthreads();

#pragma unroll
    for (int ks = 0; ks < 2; ks++) {
      const int slot = ((ks * 4 + lg) ^ (lq & 7)) * 8;
      bf16x8 af[4], bfr[4];
#pragma unroll
      for (int m = 0; m < 4; m++)
        af[m] = *(const bf16x8*)(As + (wr * 64 + m * 16 + lq) * 64 + slot);
#pragma unroll
      for (int n = 0; n < 4; n++)
        bfr[n] = *(const bf16x8*)(Bs + (wc * 64 + n * 16 + lq) * 64 + slot);
#pragma unroll
      for (int m = 0; m < 4; m++)
#pragma unroll
        for (int n = 0; n < 4; n++)
          acc[m][n] = __builtin_amdgcn_mfma_f32_16x16x32_bf16(af[m], bfr[n], acc[m][n], 0, 0, 0);
    }
  }

#pragma unroll
  for (int m = 0; m < 4; m++) {
    const int row = tm * 128 + wr * 64 + m * 16 + lg * 4;
#pragma unroll
    for (int i = 0; i < 4; i++) {
      u16* cp = C + (size_t)(row + i) * N + tn * 128 + wc * 64 + lq;
#pragma unroll
      for (int n = 0; n < 4; n++)
        cp[n * 16] = f2bf(acc[m][n][i] * scale);
    }
  }
}

// ---------------- fused Q/K/VT projection GEMMs (768 blocks) ----------------
__global__ __launch_bounds__(256, 3) void qkv_gemm(const u16* __restrict__ xb,
                                                   const u16* __restrict__ zb,
                                                   const u16* __restrict__ Wqb,
                                                   const u16* __restrict__ Wkvb,
                                                   u16* __restrict__ Qb,
                                                   u16* __restrict__ Kb,
                                                   u16* __restrict__ VTb) {
  __shared__ __align__(16) u16 As[128 * 64];
  __shared__ __align__(16) u16 Bs[128 * 64];
  int g = blockIdx.x;
  if (g < 256) {
    // Q = (0.125*log2e) * x @ Wq^T   [4096 x 1024]
    gemm64_body(xb, Wqb, Qb, 1024, 1024, QSCALE, g >> 3, g & 7, As, Bs);
  } else if (g < 512) {
    g -= 256;  // K = z @ Wk^T   [4096 x 1024]
    gemm64_body(zb, Wkvb, Kb, 1024, 512, 1.f, g >> 3, g & 7, As, Bs);
  } else {
    g -= 512;  // VT = Wv @ z^T  [1024 x 4096]
    gemm64_body(Wkvb + 1024 * 512, zb, VTb, 4096, 512, 1.f, g >> 5, g & 31, As, Bs);
  }
}

// ---------------- O-GEMM with fused split-KV combine ------------------------
// out[row][n] = sum_d (w0*OP0[row][d] + w1*OP1[row][d]) * Wo[n][d]
// A is reg-staged (combine in registers, swizzled ds_write); B via gload_lds.
// 128x64 tiles, BK=32, grid (16, 32).
__global__ __launch_bounds__(256) void o_gemm_combine(const u16* __restrict__ OP,
                                                      const float2* __restrict__ ml,
                                                      const u16* __restrict__ Wob,
                                                      float* __restrict__ out) {
  __shared__ __align__(16) u16 As[128 * 32];
  __shared__ __align__(16) u16 Bs[64 * 32];
  const int tid = threadIdx.x;
  const int wid = tid >> 6;
  const int lane = tid & 63;
  const int lg = lane >> 4, lq = lane & 15;
  const int wr = wid >> 1, wc = wid & 1;
  const int tm = blockIdx.y, tn = blockIdx.x;

  f32x4 acc[4][2];
#pragma unroll
  for (int m = 0; m < 4; m++)
#pragma unroll
    for (int n = 0; n < 2; n++)
#pragma unroll
      for (int e = 0; e < 4; e++) acc[m][n][e] = 0.f;

  const int r0 = tid >> 2;                    // 0..63
  const int c0 = tid & 3;                     // chunk 0..3
  const int slotA = c0 ^ ((r0 >> 1) & 3);     // ds_write slot (same for r0+64)
  const int grow0 = tm * 128 + r0;

  const u16* gO00 = OP + (size_t)grow0 * 1024;                    // split0, row grow0
  const u16* gO01 = gO00 + (size_t)4096 * 1024;                   // split1
  const u16* gO10 = gO00 + (size_t)64 * 1024;                     // split0, row grow0+64
  const u16* gO11 = gO01 + (size_t)64 * 1024;
  const float2* mlr0 = ml + (size_t)grow0 * 16;
  const float2* mlr1 = mlr0 + 64 * 16;

  // B staging: pre-swizzled source, linear LDS
  const u16* gB = Wob + (size_t)(tn * 64 + r0) * 1024 + slotA * 8;
  u16* lB = Bs + wid * 512;

  const int rslot = (lg ^ ((lq >> 1) & 3)) * 8;

  for (int k0 = 0; k0 < 1024; k0 += 32) {
    const int col = k0 + c0 * 8;
    const int h = k0 >> 6;
    __syncthreads();
    // issue A loads (global->reg) + B gload
    bf16x8 p00 = *(const bf16x8*)(gO00 + col);
    bf16x8 p01 = *(const bf16x8*)(gO01 + col);
    bf16x8 p10 = *(const bf16x8*)(gO10 + col);
    bf16x8 p11 = *(const bf16x8*)(gO11 + col);
    const float2 a0 = mlr0[h], b0 = mlr0[65536 + h];
    const float2 a1 = mlr1[h], b1 = mlr1[65536 + h];
    gload_lds16(gB + k0, lB);

    // combine weights per row
    float M0 = fmaxf(a0.x, b0.x);
    float w00 = a0.y * fast_exp2(a0.x - M0);
    float w01 = b0.y * fast_exp2(b0.x - M0);
    float i0 = 1.f / (w00 + w01); w00 *= i0; w01 *= i0;
    float M1 = fmaxf(a1.x, b1.x);
    float w10 = a1.y * fast_exp2(a1.x - M1);
    float w11 = b1.y * fast_exp2(b1.x - M1);
    float i1 = 1.f / (w10 + w11); w10 *= i1; w11 *= i1;

    union { bf16x8 v; uint32_t d[4]; } A0, A1;
#pragma unroll
    for (int e = 0; e < 8; e += 2) {
      float f0 = w00 * bf2f((u16)p00[e])     + w01 * bf2f((u16)p01[e]);
      float f1 = w00 * bf2f((u16)p00[e + 1]) + w01 * bf2f((u16)p01[e + 1]);
      A0.d[e >> 1] = cvtpk(f0, f1);
      float g0 = w10 * bf2f((u16)p10[e])     + w11 * bf2f((u16)p11[e]);
      float g1 = w10 * bf2f((u16)p10[e + 1]) + w11 * bf2f((u16)p11[e + 1]);
      A1.d[e >> 1] = cvtpk(g0, g1);
    }
    *(bf16x8*)(As + r0 * 32 + slotA * 8) = A0.v;
    *(bf16x8*)(As + (r0 + 64) * 32 + slotA * 8) = A1.v;
    __syncthreads();

    bf16x8 af[4], bfr[2];
#pragma unroll
    for (int m = 0; m < 4; m++)
      af[m] = *(const bf16x8*)(As + (wr * 64 + m * 16 + lq) * 32 + rslot);
#pragma unroll
    for (int n = 0; n < 2; n++)
      bfr[n] = *(const bf16x8*)(Bs + (wc * 32 + n * 16 + lq) * 32 + rslot);
#pragma unroll
    for (int m = 0; m < 4; m++)
#pragma unroll
      for (int n = 0; n < 2; n++)
        acc[m][n] = __builtin_amdgcn_mfma_f32_16x16x32_bf16(af[m], bfr[n], acc[m][n], 0, 0, 0);
  }

#pragma unroll
  for (int m = 0; m < 4; m++) {
    const int row = tm * 128 + wr * 64 + m * 16 + lg * 4;
#pragma unroll
    for (int i = 0; i < 4; i++) {
      float* cp = out + (size_t)(row + i) * 1024 + tn * 64 + wc * 32 + lq;
#pragma unroll
      for (int n = 0; n < 2; n++) cp[n * 16] = acc[m][n][i];
    }
  }
}

// ---------------- flash attention, split-KV x2 ------------------------------
// Q : [B*SEQ][1024] bf16 (pre-scaled by 0.125*log2e); K : [B*SEQ][1024] bf16
// VT: [1024][B*SEQ] bf16
// OP: per-split normalized O partials, [2][4096][1024] bf16
// ml: [2][4096][16] float2 {m, l} per (split, row, head)
// 1024 blocks (4/CU), 4 waves x 32 q = 128 q/block, 16 KV-tiles per split.
__global__ __launch_bounds__(256, 4) void attn_kernel(const u16* __restrict__ Q,
                                                      const u16* __restrict__ K,
                                                      const u16* __restrict__ VT,
                                                      u16* __restrict__ OP,
                                                      float2* __restrict__ ml) {
  // LDS bytes: K0@0, K1@8192, V0@16384, V1@24576
  __shared__ __align__(16) u16 LDS[16384];

  const int tid = threadIdx.x;
  const int wid = tid >> 6;
  const int lane = tid & 63;
  const int l31 = lane & 31;
  const int hi = lane >> 5;

  // XCD-bijective decode: (xcd | qt | split | bh-group)
  const int bi = blockIdx.x;
  const int xcd = bi & 7, j = bi >> 3;       // j: 0..127
  const int qt = j & 15;
  const int s  = (j >> 4) & 1;
  const int bh = xcd + 8 * (j >> 5);         // 0..31
  const int b = bh >> 4, h = bh & 15;
  const int t0 = s * 16;

  const int q0 = qt * 128 + wid * 32;

  // Q fragments (B-operand): col q = l31, k-elems d = ks*16 + hi*8 .. +7
  bf16x8 qf[4];
  {
    const u16* qp = Q + (size_t)(b * SEQ + q0 + l31) * 1024 + h * 64 + hi * 8;
#pragma unroll
    for (int ks = 0; ks < 4; ks++) qf[ks] = *(const bf16x8*)(qp + ks * 16);
  }

  f32x16 of[2];
#pragma unroll
  for (int d = 0; d < 2; d++)
#pragma unroll
    for (int e = 0; e < 16; e++) of[d][e] = 0.f;
  float m_run = -3.0e38f, l_run = 0.f;

  // tile-invariant per-lane LDS read bases (row l31, swizzled chunk)
  const char* rdB[4];
#pragma unroll
  for (int ks = 0; ks < 4; ks++)
    rdB[ks] = (const char*)LDS + l31 * 128 + ((((2 * ks + hi) ^ (lane & 7))) << 4);

  // staging: wave w stages rows 8w..8w+7 (+32), pre-swizzled source column
  const int r0 = tid >> 3;
  const int srcc = ((tid & 7) ^ (r0 & 7)) << 3;
  const u16* gK = K + (size_t)(b * SEQ + r0) * 1024 + h * 64 + srcc;
  const u16* gV = VT + (size_t)(h * 64 + r0) * 4096 + b * SEQ + srcc;
  u16* lK = LDS + wid * 512;
  u16* lV = LDS + 8192 + wid * 512;

  auto stage = [&](int t, int buf) {
    const u16* sk = gK + (size_t)t * 64 * 1024;
    gload_lds16(sk, lK + buf * 4096);
    gload_lds16(sk + (size_t)32 * 1024, lK + buf * 4096 + 2048);
    const u16* sv = gV + t * 64;
    gload_lds16(sv, lV + buf * 4096);
    gload_lds16(sv + (size_t)32 * 4096, lV + buf * 4096 + 2048);
  };

  auto tile_compute = [&](int buf) {
    const int bo = buf * 8192;   // bytes

    // S^T = K (A) x Q (B): col = q = l31, row = key = kb*32 + (r&3)+8*(r>>2)+4*hi
    f32x16 sacc[2];
#pragma unroll
    for (int kb = 0; kb < 2; kb++)
#pragma unroll
      for (int e = 0; e < 16; e++) sacc[kb][e] = 0.f;
    __builtin_amdgcn_s_setprio(1);
#pragma unroll
    for (int kb = 0; kb < 2; kb++)
#pragma unroll
      for (int ks = 0; ks < 4; ks++) {
        bf16x8 kf = *(const bf16x8*)(rdB[ks] + bo + kb * 4096);
        sacc[kb] = __builtin_amdgcn_mfma_f32_32x32x16_bf16(kf, qf[ks], sacc[kb], 0, 0, 0);
      }
    __builtin_amdgcn_s_setprio(0);

    // hoist V-fragment loads off the softmax critical path
    bf16x8 vf0[4], vf1[4];
#pragma unroll
    for (int ks = 0; ks < 4; ks++) {
      vf0[ks] = *(const bf16x8*)(rdB[ks] + bo + 16384);
      vf1[ks] = *(const bf16x8*)(rdB[ks] + bo + 16384 + 4096);
    }

    // tree max over 32 scores (4 parallel chains), then lane^32 pair combine
    float a0 = sacc[0][0], a1 = sacc[0][1], a2 = sacc[0][2], a3 = sacc[0][3];
#pragma unroll
    for (int e = 4; e < 16; e += 4) {
      a0 = fmaxf(a0, sacc[0][e]);     a1 = fmaxf(a1, sacc[0][e + 1]);
      a2 = fmaxf(a2, sacc[0][e + 2]); a3 = fmaxf(a3, sacc[0][e + 3]);
    }
#pragma unroll
    for (int e = 0; e < 16; e += 4) {
      a0 = fmaxf(a0, sacc[1][e]);     a1 = fmaxf(a1, sacc[1][e + 1]);
      a2 = fmaxf(a2, sacc[1][e + 2]); a3 = fmaxf(a3, sacc[1][e + 3]);
    }
    float tmax = fmaxf(fmaxf(a0, a1), fmaxf(a2, a3));
    tmax = fmaxf(tmax, __shfl_xor(tmax, 32));

    if (!__all(tmax <= m_run + DEFER_THR)) {   // defer-max (T13)
      const float m_new = fmaxf(m_run, tmax);
      const float esc = fast_exp2(m_run - m_new);
      l_run *= esc;
#pragma unroll
      for (int r = 0; r < 16; r++) {
        const int qof = (r & 3) + 8 * (r >> 2) + 4 * hi;
        const float e = __shfl(esc, qof);
        of[0][r] *= e;
        of[1][r] *= e;
      }
      m_run = m_new;
    }

    // p = exp2(s - m); psum via 4 parallel chains
    float s0 = 0.f, s1 = 0.f, s2 = 0.f, s3 = 0.f;
#pragma unroll
    for (int kb = 0; kb < 2; kb++)
#pragma unroll
      for (int e = 0; e < 16; e += 4) {
        float p0 = fast_exp2(sacc[kb][e] - m_run);
        float p1 = fast_exp2(sacc[kb][e + 1] - m_run);
        float p2 = fast_exp2(sacc[kb][e + 2] - m_run);
        float p3 = fast_exp2(sacc[kb][e + 3] - m_run);
        sacc[kb][e] = p0; sacc[kb][e + 1] = p1; sacc[kb][e + 2] = p2; sacc[kb][e + 3] = p3;
        s0 += p0; s1 += p1; s2 += p2; s3 += p3;
      }
    l_run += (s0 + s1) + (s2 + s3);

    // pack P to bf16 A-fragments in-register (cvt_pk + shfl_xor exchange)
    bf16x8 pa[4];
#pragma unroll
    for (int kb = 0; kb < 2; kb++) {
      uint32_t c0 = cvtpk(sacc[kb][0],  sacc[kb][1]);
      uint32_t c1 = cvtpk(sacc[kb][2],  sacc[kb][3]);
      uint32_t c2 = cvtpk(sacc[kb][4],  sacc[kb][5]);
      uint32_t c3 = cvtpk(sacc[kb][6],  sacc[kb][7]);
      uint32_t c4 = cvtpk(sacc[kb][8],  sacc[kb][9]);
      uint32_t c5 = cvtpk(sacc[kb][10], sacc[kb][11]);
      uint32_t c6 = cvtpk(sacc[kb][12], sacc[kb][13]);
      uint32_t c7 = cvtpk(sacc[kb][14], sacc[kb][15]);
      swap_pair(c0, c2, hi);
      swap_pair(c1, c3, hi);
      swap_pair(c4, c6, hi);
      swap_pair(c5, c7, hi);
      union { bf16x8 v; uint32_t d[4]; } u0, u1;
      u0.d[0] = c0; u0.d[1] = c1; u0.d[2] = c2; u0.d[3] = c3;
      u1.d[0] = c4; u1.d[1] = c5; u1.d[2] = c6; u1.d[3] = c7;
      pa[2 * kb] = u0.v;
      pa[2 * kb + 1] = u1.v;
    }

    // O += P (A) x V (B)
    __builtin_amdgcn_s_setprio(1);
#pragma unroll
    for (int ks = 0; ks < 4; ks++) {
      of[0] = __builtin_amdgcn_mfma_f32_32x32x16_bf16(pa[ks], vf0[ks], of[0], 0, 0, 0);
      of[1] = __builtin_amdgcn_mfma_f32_32x32x16_bf16(pa[ks], vf1[ks], of[1], 0, 0, 0);
    }
    __builtin_amdgcn_s_setprio(0);
  };

  stage(t0, 0);
  __syncthreads();
#pragma unroll 1
  for (int tt = 0; tt < 16; tt += 2) {
    stage(t0 + tt + 1, 1);
    tile_compute(0);
    __syncthreads();
    if (tt < 14) stage(t0 + tt + 2, 0);
    tile_compute(1);
    __syncthreads();
  }

  // per-split finalize: normalized partial + (m, l)
  const float lsum = l_run + __shfl_xor(l_run, 32);
  const float linv = 1.f / lsum;

  u16* OPs = OP + (size_t)s * 4096 * 1024;
#pragma unroll
  for (int r = 0; r < 16; r++) {
    const int qof = (r & 3) + 8 * (r >> 2) + 4 * hi;
    const float li = __shfl(linv, qof);
    u16* op = OPs + (size_t)(b * SEQ + q0 + qof) * 1024 + h * 64 + l31;
    op[0]  = f2bf(of[0][r] * li);
    op[32] = f2bf(of[1][r] * li);
  }
  if (hi == 0) {
    const int grow = b * SEQ + q0 + l31;
    ml[s * (4096 * 16) + grow * 16 + h] = make_float2(m_run, lsum);
  }
}

// ---------------- launch ----------------
extern "C" void kernel_launch(void* const* d_in, const int* in_sizes, int n_in,
                              void* d_out, int out_size, void* d_ws, size_t ws_size,
                              hipStream_t stream) {
  const float* x   = (const float*)d_in[0];
  const float* z   = (const float*)d_in[1];
  const float* Wq  = (const float*)d_in[2];
  const float* Wkv = (const float*)d_in[3];
  const float* Wo  = (const float*)d_in[4];
  float* out = (float*)d_out;

  char* ws = (char*)d_ws;
  const size_t MB = 1024ull * 1024ull;
  u16* xb   = (u16*)(ws + 0);        // 8 MB  [4096][1024]   (dead after qkv_gemm)
  u16* zb   = (u16*)(ws + 8 * MB);   // 4 MB  [4096][512]    (dead after qkv_gemm)
  u16* Wqb  = (u16*)(ws + 12 * MB);  // 2 MB                 (dead after qkv_gemm)
  u16* Wkvb = (u16*)(ws + 14 * MB);  // 2 MB                 (dead after qkv_gemm)
  u16* Wob  = (u16*)(ws + 16 * MB);  // 2 MB
  u16* Qb   = (u16*)(ws + 18 * MB);  // 8 MB  [4096][1024] (pre-scaled, log2 domain)
  u16* Kb   = (u16*)(ws + 26 * MB);  // 8 MB  [4096][1024]
  u16* VTb  = (u16*)(ws + 34 * MB);  // 8 MB  [1024][4096]
  u16* OP   = (u16*)(ws + 0);        // 16 MB [2][4096][1024] partials (reuse xb..Wkvb)
  float2* ml = (float2*)(ws + 50 * MB);  // 1 MB [2][4096][16]

  cvt5_kernel<<<2048, 256, 0, stream>>>(x, z, Wq, Wkv, Wo, xb, zb, Wqb, Wkvb, Wob);

  qkv_gemm<<<768, 256, 0, stream>>>(xb, zb, Wqb, Wkvb, Qb, Kb, VTb);

  attn_kernel<<<1024, 256, 0, stream>>>(Qb, Kb, VTb, OP, ml);

  o_gemm_combine<<<dim3(16, 32), 256, 0, stream>>>(OP, ml, Wob, out);
}

// Round 11
// 137.901 us; speedup vs baseline: 1.1855x; 1.1855x over previous
//
#include <hip/hip_runtime.h>
#include <stdint.h>

#define SEQ 2048
#define QSCALE 0.1803368801111244f   // 0.125 * log2(e)
#define DEFER_THR 11.5f              // 8 nats in log2 units

typedef __attribute__((ext_vector_type(8))) short bf16x8;
typedef __attribute__((ext_vector_type(4))) short bf16x4;
typedef __attribute__((ext_vector_type(4))) float f32x4;
typedef __attribute__((ext_vector_type(16))) float f32x16;
typedef unsigned short u16;

__device__ __forceinline__ u16 f2bf(float f) {
  union { float f; uint32_t u; } v; v.f = f;
  uint32_t u = v.u;
  u += 0x7fffu + ((u >> 16) & 1u);   // RNE
  return (u16)(u >> 16);
}

__device__ __forceinline__ float bf2f(u16 b) {
  union { uint32_t u; float f; } v;
  v.u = ((uint32_t)b) << 16;
  return v.f;
}

__device__ __forceinline__ float fast_exp2(float x) {
#if __has_builtin(__builtin_amdgcn_exp2f)
  return __builtin_amdgcn_exp2f(x);   // v_exp_f32 (native base-2)
#else
  return exp2f(x);
#endif
}

__device__ __forceinline__ uint32_t cvtpk(float a, float b) {
  uint32_t r;
  asm("v_cvt_pk_bf16_f32 %0, %1, %2" : "=v"(r) : "v"(a), "v"(b));
  return r;
}

// exchange across lane<->lane^32 (R5-verified semantics, shfl-based):
// a' = (hi ? partner_b : a), b' = (hi ? b : partner_a)
__device__ __forceinline__ void swap_pair(uint32_t& a, uint32_t& b, int hi) {
  uint32_t ta = (uint32_t)__shfl_xor((int)a, 32);
  uint32_t tb = (uint32_t)__shfl_xor((int)b, 32);
  a = hi ? tb : a;
  b = hi ? b : ta;
}

__device__ __forceinline__ void gload_lds16(const u16* g, u16* l) {
  __builtin_amdgcn_global_load_lds((__attribute__((address_space(1))) void*)g,
                                   (__attribute__((address_space(3))) void*)l,
                                   16, 0, 0);
}

// ---------------- fused fp32 -> bf16 convert (all 5 tensors, 1 launch) -----
__global__ void cvt5_kernel(const float* __restrict__ x, const float* __restrict__ z,
                            const float* __restrict__ Wq, const float* __restrict__ Wkv,
                            const float* __restrict__ Wo,
                            u16* __restrict__ xb, u16* __restrict__ zb,
                            u16* __restrict__ wqb, u16* __restrict__ wkvb,
                            u16* __restrict__ wob) {
  const int X4 = 1048576, Z4 = 524288, W4 = 262144;
  const int total = X4 + Z4 + 3 * W4;
  int i = blockIdx.x * blockDim.x + threadIdx.x;
  const int stride = gridDim.x * blockDim.x;
  for (; i < total; i += stride) {
    const float* src; u16* dst; int j = i;
    if (j < X4)              { src = x;   dst = xb; }
    else if ((j -= X4) < Z4) { src = z;   dst = zb; }
    else if ((j -= Z4) < W4) { src = Wq;  dst = wqb; }
    else if ((j -= W4) < W4) { src = Wkv; dst = wkvb; }
    else       { j -= W4;      src = Wo;  dst = wob; }
    float4 v = ((const float4*)src)[j];
    bf16x4 o;
    o[0] = (short)f2bf(v.x); o[1] = (short)f2bf(v.y);
    o[2] = (short)f2bf(v.z); o[3] = (short)f2bf(v.w);
    ((bf16x4*)dst)[j] = o;
  }
}

// ---------------- C = scale * A(MxK) @ B(NxK)^T body, 128x128 tile, BK=64 --
// Staging swizzle: chunk c of row r stored at LDS position c, sourced from
// global chunk c^(r&7) (pre-swizzled source, linear LDS). Read: global chunk
// (ks*4+lg) of row (..+lq) is at position (ks*4+lg)^(lq&7).
__device__ __forceinline__ void gemm64_body(const u16* __restrict__ A,
                                            const u16* __restrict__ B,
                                            u16* __restrict__ C,
                                            int N, int K, float scale,
                                            int tm, int tn, u16* As, u16* Bs) {
  const int tid = threadIdx.x;
  const int wid = tid >> 6;
  const int lane = tid & 63;
  const int lg = lane >> 4, lq = lane & 15;
  const int wr = wid >> 1, wc = wid & 1;

  f32x4 acc[4][4];
#pragma unroll
  for (int m = 0; m < 4; m++)
#pragma unroll
    for (int n = 0; n < 4; n++)
#pragma unroll
      for (int e = 0; e < 4; e++) acc[m][n][e] = 0.f;

  const int r0 = tid >> 3;                 // 0..31
  const int c0 = tid & 7;                  // chunk 0..7
  const int sc = (c0 ^ (r0 & 7)) * 8;      // pre-swizzled source column
  const u16* gA = A + (size_t)(tm * 128 + r0) * K + sc;
  const u16* gB = B + (size_t)(tn * 128 + r0) * K + sc;
  u16* lA = As + wid * 512;                // linear LDS dest (512 u16/wave)
  u16* lB = Bs + wid * 512;

  for (int k0 = 0; k0 < K; k0 += 64) {
    __syncthreads();
#pragma unroll
    for (int i = 0; i < 4; i++) {
      // row-block i (32 rows x 64 cols = 2048 u16)
      gload_lds16(gA + k0 + (size_t)(32 * i) * K, lA + i * 2048);
      gload_lds16(gB + k0 + (size_t)(32 * i) * K, lB + i * 2048);
    }
    __syncthreads();

#pragma unroll
    for (int ks = 0; ks < 2; ks++) {
      const int slot = ((ks * 4 + lg) ^ (lq & 7)) * 8;
      bf16x8 af[4], bfr[4];
#pragma unroll
      for (int m = 0; m < 4; m++)
        af[m] = *(const bf16x8*)(As + (wr * 64 + m * 16 + lq) * 64 + slot);
#pragma unroll
      for (int n = 0; n < 4; n++)
        bfr[n] = *(const bf16x8*)(Bs + (wc * 64 + n * 16 + lq) * 64 + slot);
#pragma unroll
      for (int m = 0; m < 4; m++)
#pragma unroll
        for (int n = 0; n < 4; n++)
          acc[m][n] = __builtin_amdgcn_mfma_f32_16x16x32_bf16(af[m], bfr[n], acc[m][n], 0, 0, 0);
    }
  }

#pragma unroll
  for (int m = 0; m < 4; m++) {
    const int row = tm * 128 + wr * 64 + m * 16 + lg * 4;
#pragma unroll
    for (int i = 0; i < 4; i++) {
      u16* cp = C + (size_t)(row + i) * N + tn * 128 + wc * 64 + lq;
#pragma unroll
      for (int n = 0; n < 4; n++)
        cp[n * 16] = f2bf(acc[m][n][i] * scale);
    }
  }
}

// ---------------- fused Q/K/VT projection GEMMs (768 blocks) ----------------
__global__ __launch_bounds__(256, 3) void qkv_gemm(const u16* __restrict__ xb,
                                                   const u16* __restrict__ zb,
                                                   const u16* __restrict__ Wqb,
                                                   const u16* __restrict__ Wkvb,
                                                   u16* __restrict__ Qb,
                                                   u16* __restrict__ Kb,
                                                   u16* __restrict__ VTb) {
  __shared__ __align__(16) u16 As[128 * 64];
  __shared__ __align__(16) u16 Bs[128 * 64];
  int g = blockIdx.x;
  if (g < 256) {
    // Q = (0.125*log2e) * x @ Wq^T   [4096 x 1024]
    gemm64_body(xb, Wqb, Qb, 1024, 1024, QSCALE, g >> 3, g & 7, As, Bs);
  } else if (g < 512) {
    g -= 256;  // K = z @ Wk^T   [4096 x 1024]
    gemm64_body(zb, Wkvb, Kb, 1024, 512, 1.f, g >> 3, g & 7, As, Bs);
  } else {
    g -= 512;  // VT = Wv @ z^T  [1024 x 4096]
    gemm64_body(Wkvb + 1024 * 512, zb, VTb, 4096, 512, 1.f, g >> 5, g & 31, As, Bs);
  }
}

// ---------------- O-GEMM with fused split-KV combine ------------------------
// out[row][n] = sum_d (w0*OP0[row][d] + w1*OP1[row][d]) * Wo[n][d]
// A is reg-staged (combine in registers, swizzled ds_write); B via gload_lds.
// 128x64 tiles, BK=32, grid (16, 32).
__global__ __launch_bounds__(256) void o_gemm_combine(const u16* __restrict__ OP,
                                                      const float2* __restrict__ ml,
                                                      const u16* __restrict__ Wob,
                                                      float* __restrict__ out) {
  __shared__ __align__(16) u16 As[128 * 32];
  __shared__ __align__(16) u16 Bs[64 * 32];
  const int tid = threadIdx.x;
  const int wid = tid >> 6;
  const int lane = tid & 63;
  const int lg = lane >> 4, lq = lane & 15;
  const int wr = wid >> 1, wc = wid & 1;
  const int tm = blockIdx.y, tn = blockIdx.x;

  f32x4 acc[4][2];
#pragma unroll
  for (int m = 0; m < 4; m++)
#pragma unroll
    for (int n = 0; n < 2; n++)
#pragma unroll
      for (int e = 0; e < 4; e++) acc[m][n][e] = 0.f;

  const int r0 = tid >> 2;                    // 0..63
  const int c0 = tid & 3;                     // chunk 0..3
  const int slotA = c0 ^ ((r0 >> 1) & 3);     // ds_write slot (same for r0+64)
  const int grow0 = tm * 128 + r0;

  const u16* gO00 = OP + (size_t)grow0 * 1024;                    // split0, row grow0
  const u16* gO01 = gO00 + (size_t)4096 * 1024;                   // split1
  const u16* gO10 = gO00 + (size_t)64 * 1024;                     // split0, row grow0+64
  const u16* gO11 = gO01 + (size_t)64 * 1024;
  const float2* mlr0 = ml + (size_t)grow0 * 16;
  const float2* mlr1 = mlr0 + 64 * 16;

  // B staging: pre-swizzled source, linear LDS
  const u16* gB = Wob + (size_t)(tn * 64 + r0) * 1024 + slotA * 8;
  u16* lB = Bs + wid * 512;

  const int rslot = (lg ^ ((lq >> 1) & 3)) * 8;

  for (int k0 = 0; k0 < 1024; k0 += 32) {
    const int col = k0 + c0 * 8;
    const int h = k0 >> 6;
    __syncthreads();
    // issue A loads (global->reg) + B gload
    bf16x8 p00 = *(const bf16x8*)(gO00 + col);
    bf16x8 p01 = *(const bf16x8*)(gO01 + col);
    bf16x8 p10 = *(const bf16x8*)(gO10 + col);
    bf16x8 p11 = *(const bf16x8*)(gO11 + col);
    const float2 a0 = mlr0[h], b0 = mlr0[65536 + h];
    const float2 a1 = mlr1[h], b1 = mlr1[65536 + h];
    gload_lds16(gB + k0, lB);

    // combine weights per row
    float M0 = fmaxf(a0.x, b0.x);
    float w00 = a0.y * fast_exp2(a0.x - M0);
    float w01 = b0.y * fast_exp2(b0.x - M0);
    float i0 = 1.f / (w00 + w01); w00 *= i0; w01 *= i0;
    float M1 = fmaxf(a1.x, b1.x);
    float w10 = a1.y * fast_exp2(a1.x - M1);
    float w11 = b1.y * fast_exp2(b1.x - M1);
    float i1 = 1.f / (w10 + w11); w10 *= i1; w11 *= i1;

    union { bf16x8 v; uint32_t d[4]; } A0, A1;
#pragma unroll
    for (int e = 0; e < 8; e += 2) {
      float f0 = w00 * bf2f((u16)p00[e])     + w01 * bf2f((u16)p01[e]);
      float f1 = w00 * bf2f((u16)p00[e + 1]) + w01 * bf2f((u16)p01[e + 1]);
      A0.d[e >> 1] = cvtpk(f0, f1);
      float g0 = w10 * bf2f((u16)p10[e])     + w11 * bf2f((u16)p11[e]);
      float g1 = w10 * bf2f((u16)p10[e + 1]) + w11 * bf2f((u16)p11[e + 1]);
      A1.d[e >> 1] = cvtpk(g0, g1);
    }
    *(bf16x8*)(As + r0 * 32 + slotA * 8) = A0.v;
    *(bf16x8*)(As + (r0 + 64) * 32 + slotA * 8) = A1.v;
    __syncthreads();

    bf16x8 af[4], bfr[2];
#pragma unroll
    for (int m = 0; m < 4; m++)
      af[m] = *(const bf16x8*)(As + (wr * 64 + m * 16 + lq) * 32 + rslot);
#pragma unroll
    for (int n = 0; n < 2; n++)
      bfr[n] = *(const bf16x8*)(Bs + (wc * 32 + n * 16 + lq) * 32 + rslot);
#pragma unroll
    for (int m = 0; m < 4; m++)
#pragma unroll
      for (int n = 0; n < 2; n++)
        acc[m][n] = __builtin_amdgcn_mfma_f32_16x16x32_bf16(af[m], bfr[n], acc[m][n], 0, 0, 0);
  }

#pragma unroll
  for (int m = 0; m < 4; m++) {
    const int row = tm * 128 + wr * 64 + m * 16 + lg * 4;
#pragma unroll
    for (int i = 0; i < 4; i++) {
      float* cp = out + (size_t)(row + i) * 1024 + tn * 64 + wc * 32 + lq;
#pragma unroll
      for (int n = 0; n < 2; n++) cp[n * 16] = acc[m][n][i];
    }
  }
}

// ---------------- flash attention, split-KV x2 (R8 tile_compute, no hoist) --
// Q : [B*SEQ][1024] bf16 (pre-scaled by 0.125*log2e); K : [B*SEQ][1024] bf16
// VT: [1024][B*SEQ] bf16
// OP: per-split normalized O partials, [2][4096][1024] bf16
// ml: [2][4096][16] float2 {m, l} per (split, row, head)
// 1024 blocks (4/CU), 4 waves x 32 q = 128 q/block, 16 KV-tiles per split.
__global__ __launch_bounds__(256, 4) void attn_kernel(const u16* __restrict__ Q,
                                                      const u16* __restrict__ K,
                                                      const u16* __restrict__ VT,
                                                      u16* __restrict__ OP,
                                                      float2* __restrict__ ml) {
  // LDS bytes: K0@0, K1@8192, V0@16384, V1@24576
  __shared__ __align__(16) u16 LDS[16384];

  const int tid = threadIdx.x;
  const int wid = tid >> 6;
  const int lane = tid & 63;
  const int l31 = lane & 31;
  const int hi = lane >> 5;

  // XCD-bijective decode: (xcd | qt | split | bh-group)
  const int bi = blockIdx.x;
  const int xcd = bi & 7, j = bi >> 3;       // j: 0..127
  const int qt = j & 15;
  const int s  = (j >> 4) & 1;
  const int bh = xcd + 8 * (j >> 5);         // 0..31
  const int b = bh >> 4, h = bh & 15;
  const int t0 = s * 16;

  const int q0 = qt * 128 + wid * 32;

  // Q fragments (B-operand): col q = l31, k-elems d = ks*16 + hi*8 .. +7
  bf16x8 qf[4];
  {
    const u16* qp = Q + (size_t)(b * SEQ + q0 + l31) * 1024 + h * 64 + hi * 8;
#pragma unroll
    for (int ks = 0; ks < 4; ks++) qf[ks] = *(const bf16x8*)(qp + ks * 16);
  }

  f32x16 of[2];
#pragma unroll
  for (int d = 0; d < 2; d++)
#pragma unroll
    for (int e = 0; e < 16; e++) of[d][e] = 0.f;
  float m_run = -3.0e38f, l_run = 0.f;

  // tile-invariant per-lane LDS read bases (row l31, swizzled chunk)
  const char* rdB[4];
#pragma unroll
  for (int ks = 0; ks < 4; ks++)
    rdB[ks] = (const char*)LDS + l31 * 128 + ((((2 * ks + hi) ^ (lane & 7))) << 4);

  // staging: wave w stages rows 8w..8w+7 (+32), pre-swizzled source column
  const int r0 = tid >> 3;
  const int srcc = ((tid & 7) ^ (r0 & 7)) << 3;
  const u16* gK = K + (size_t)(b * SEQ + r0) * 1024 + h * 64 + srcc;
  const u16* gV = VT + (size_t)(h * 64 + r0) * 4096 + b * SEQ + srcc;
  u16* lK = LDS + wid * 512;
  u16* lV = LDS + 8192 + wid * 512;

  auto stage = [&](int t, int buf) {
    const u16* sk = gK + (size_t)t * 64 * 1024;
    gload_lds16(sk, lK + buf * 4096);
    gload_lds16(sk + (size_t)32 * 1024, lK + buf * 4096 + 2048);
    const u16* sv = gV + t * 64;
    gload_lds16(sv, lV + buf * 4096);
    gload_lds16(sv + (size_t)32 * 4096, lV + buf * 4096 + 2048);
  };

  auto tile_compute = [&](int buf) {
    const int bo = buf * 8192;   // bytes

    // S^T = K (A) x Q (B): col = q = l31, row = key = kb*32 + (r&3)+8*(r>>2)+4*hi
    f32x16 sacc[2];
#pragma unroll
    for (int kb = 0; kb < 2; kb++)
#pragma unroll
      for (int e = 0; e < 16; e++) sacc[kb][e] = 0.f;
    __builtin_amdgcn_s_setprio(1);
#pragma unroll
    for (int kb = 0; kb < 2; kb++)
#pragma unroll
      for (int ks = 0; ks < 4; ks++) {
        bf16x8 kf = *(const bf16x8*)(rdB[ks] + bo + kb * 4096);
        sacc[kb] = __builtin_amdgcn_mfma_f32_32x32x16_bf16(kf, qf[ks], sacc[kb], 0, 0, 0);
      }
    __builtin_amdgcn_s_setprio(0);

    // tree max over 32 scores (4 parallel chains), then lane^32 pair combine
    float a0 = sacc[0][0], a1 = sacc[0][1], a2 = sacc[0][2], a3 = sacc[0][3];
#pragma unroll
    for (int e = 4; e < 16; e += 4) {
      a0 = fmaxf(a0, sacc[0][e]);     a1 = fmaxf(a1, sacc[0][e + 1]);
      a2 = fmaxf(a2, sacc[0][e + 2]); a3 = fmaxf(a3, sacc[0][e + 3]);
    }
#pragma unroll
    for (int e = 0; e < 16; e += 4) {
      a0 = fmaxf(a0, sacc[1][e]);     a1 = fmaxf(a1, sacc[1][e + 1]);
      a2 = fmaxf(a2, sacc[1][e + 2]); a3 = fmaxf(a3, sacc[1][e + 3]);
    }
    float tmax = fmaxf(fmaxf(a0, a1), fmaxf(a2, a3));
    tmax = fmaxf(tmax, __shfl_xor(tmax, 32));

    if (!__all(tmax <= m_run + DEFER_THR)) {   // defer-max (T13)
      const float m_new = fmaxf(m_run, tmax);
      const float esc = fast_exp2(m_run - m_new);
      l_run *= esc;
#pragma unroll
      for (int r = 0; r < 16; r++) {
        const int qof = (r & 3) + 8 * (r >> 2) + 4 * hi;
        const float e = __shfl(esc, qof);
        of[0][r] *= e;
        of[1][r] *= e;
      }
      m_run = m_new;
    }

    // p = exp2(s - m); psum via 4 parallel chains
    float s0 = 0.f, s1 = 0.f, s2 = 0.f, s3 = 0.f;
#pragma unroll
    for (int kb = 0; kb < 2; kb++)
#pragma unroll
      for (int e = 0; e < 16; e += 4) {
        float p0 = fast_exp2(sacc[kb][e] - m_run);
        float p1 = fast_exp2(sacc[kb][e + 1] - m_run);
        float p2 = fast_exp2(sacc[kb][e + 2] - m_run);
        float p3 = fast_exp2(sacc[kb][e + 3] - m_run);
        sacc[kb][e] = p0; sacc[kb][e + 1] = p1; sacc[kb][e + 2] = p2; sacc[kb][e + 3] = p3;
        s0 += p0; s1 += p1; s2 += p2; s3 += p3;
      }
    l_run += (s0 + s1) + (s2 + s3);

    // pack P to bf16 A-fragments in-register (cvt_pk + shfl_xor exchange)
    bf16x8 pa[4];
#pragma unroll
    for (int kb = 0; kb < 2; kb++) {
      uint32_t c0 = cvtpk(sacc[kb][0],  sacc[kb][1]);
      uint32_t c1 = cvtpk(sacc[kb][2],  sacc[kb][3]);
      uint32_t c2 = cvtpk(sacc[kb][4],  sacc[kb][5]);
      uint32_t c3 = cvtpk(sacc[kb][6],  sacc[kb][7]);
      uint32_t c4 = cvtpk(sacc[kb][8],  sacc[kb][9]);
      uint32_t c5 = cvtpk(sacc[kb][10], sacc[kb][11]);
      uint32_t c6 = cvtpk(sacc[kb][12], sacc[kb][13]);
      uint32_t c7 = cvtpk(sacc[kb][14], sacc[kb][15]);
      swap_pair(c0, c2, hi);
      swap_pair(c1, c3, hi);
      swap_pair(c4, c6, hi);
      swap_pair(c5, c7, hi);
      union { bf16x8 v; uint32_t d[4]; } u0, u1;
      u0.d[0] = c0; u0.d[1] = c1; u0.d[2] = c2; u0.d[3] = c3;
      u1.d[0] = c4; u1.d[1] = c5; u1.d[2] = c6; u1.d[3] = c7;
      pa[2 * kb] = u0.v;
      pa[2 * kb + 1] = u1.v;
    }

    // O += P (A) x V (B): V-frag read inline (short live range, no spill)
    __builtin_amdgcn_s_setprio(1);
#pragma unroll
    for (int ks = 0; ks < 4; ks++)
#pragma unroll
      for (int db = 0; db < 2; db++) {
        bf16x8 vf = *(const bf16x8*)(rdB[ks] + bo + 16384 + db * 4096);
        of[db] = __builtin_amdgcn_mfma_f32_32x32x16_bf16(pa[ks], vf, of[db], 0, 0, 0);
      }
    __builtin_amdgcn_s_setprio(0);
  };

  stage(t0, 0);
  __syncthreads();
#pragma unroll 1
  for (int tt = 0; tt < 16; tt += 2) {
    stage(t0 + tt + 1, 1);
    tile_compute(0);
    __syncthreads();
    if (tt < 14) stage(t0 + tt + 2, 0);
    tile_compute(1);
    __syncthreads();
  }

  // per-split finalize: normalized partial + (m, l)
  const float lsum = l_run + __shfl_xor(l_run, 32);
  const float linv = 1.f / lsum;

  u16* OPs = OP + (size_t)s * 4096 * 1024;
#pragma unroll
  for (int r = 0; r < 16; r++) {
    const int qof = (r & 3) + 8 * (r >> 2) + 4 * hi;
    const float li = __shfl(linv, qof);
    u16* op = OPs + (size_t)(b * SEQ + q0 + qof) * 1024 + h * 64 + l31;
    op[0]  = f2bf(of[0][r] * li);
    op[32] = f2bf(of[1][r] * li);
  }
  if (hi == 0) {
    const int grow = b * SEQ + q0 + l31;
    ml[s * (4096 * 16) + grow * 16 + h] = make_float2(m_run, lsum);
  }
}

// ---------------- launch ----------------
extern "C" void kernel_launch(void* const* d_in, const int* in_sizes, int n_in,
                              void* d_out, int out_size, void* d_ws, size_t ws_size,
                              hipStream_t stream) {
  const float* x   = (const float*)d_in[0];
  const float* z   = (const float*)d_in[1];
  const float* Wq  = (const float*)d_in[2];
  const float* Wkv = (const float*)d_in[3];
  const float* Wo  = (const float*)d_in[4];
  float* out = (float*)d_out;

  char* ws = (char*)d_ws;
  const size_t MB = 1024ull * 1024ull;
  u16* xb   = (u16*)(ws + 0);        // 8 MB  [4096][1024]   (dead after qkv_gemm)
  u16* zb   = (u16*)(ws + 8 * MB);   // 4 MB  [4096][512]    (dead after qkv_gemm)
  u16* Wqb  = (u16*)(ws + 12 * MB);  // 2 MB                 (dead after qkv_gemm)
  u16* Wkvb = (u16*)(ws + 14 * MB);  // 2 MB                 (dead after qkv_gemm)
  u16* Wob  = (u16*)(ws + 16 * MB);  // 2 MB
  u16* Qb   = (u16*)(ws + 18 * MB);  // 8 MB  [4096][1024] (pre-scaled, log2 domain)
  u16* Kb   = (u16*)(ws + 26 * MB);  // 8 MB  [4096][1024]
  u16* VTb  = (u16*)(ws + 34 * MB);  // 8 MB  [1024][4096]
  u16* OP   = (u16*)(ws + 0);        // 16 MB [2][4096][1024] partials (reuse xb..Wkvb)
  float2* ml = (float2*)(ws + 50 * MB);  // 1 MB [2][4096][16]

  cvt5_kernel<<<2048, 256, 0, stream>>>(x, z, Wq, Wkv, Wo, xb, zb, Wqb, Wkvb, Wob);

  qkv_gemm<<<768, 256, 0, stream>>>(xb, zb, Wqb, Wkvb, Qb, Kb, VTb);

  attn_kernel<<<1024, 256, 0, stream>>>(Qb, Kb, VTb, OP, ml);

  o_gemm_combine<<<dim3(16, 32), 256, 0, stream>>>(OP, ml, Wob, out);
}

// Round 12
// 117.533 us; speedup vs baseline: 1.3909x; 1.1733x over previous
//
#include <hip/hip_runtime.h>
#include <stdint.h>

#define SEQ 2048
#define QSCALE 0.1803368801111244f   // 0.125 * log2(e)
#define DEFER_THR 11.5f              // 8 nats in log2 units

typedef __attribute__((ext_vector_type(8))) short bf16x8;
typedef __attribute__((ext_vector_type(4))) short bf16x4;
typedef __attribute__((ext_vector_type(4))) float f32x4;
typedef __attribute__((ext_vector_type(16))) float f32x16;
typedef unsigned short u16;

__device__ __forceinline__ u16 f2bf(float f) {
  union { float f; uint32_t u; } v; v.f = f;
  uint32_t u = v.u;
  u += 0x7fffu + ((u >> 16) & 1u);   // RNE
  return (u16)(u >> 16);
}

__device__ __forceinline__ float fast_exp2(float x) {
#if __has_builtin(__builtin_amdgcn_exp2f)
  return __builtin_amdgcn_exp2f(x);   // v_exp_f32 (native base-2)
#else
  return exp2f(x);
#endif
}

__device__ __forceinline__ uint32_t cvtpk(float a, float b) {
  uint32_t r;
  asm("v_cvt_pk_bf16_f32 %0, %1, %2" : "=v"(r) : "v"(a), "v"(b));
  return r;
}

// exchange across lane<->lane^32 (R5-verified semantics, shfl-based):
// a' = (hi ? partner_b : a), b' = (hi ? b : partner_a)
__device__ __forceinline__ void swap_pair(uint32_t& a, uint32_t& b, int hi) {
  uint32_t ta = (uint32_t)__shfl_xor((int)a, 32);
  uint32_t tb = (uint32_t)__shfl_xor((int)b, 32);
  a = hi ? tb : a;
  b = hi ? b : ta;
}

__device__ __forceinline__ void gload_lds16(const u16* g, u16* l) {
  __builtin_amdgcn_global_load_lds((__attribute__((address_space(1))) void*)g,
                                   (__attribute__((address_space(3))) void*)l,
                                   16, 0, 0);
}

// ---------------- fused fp32 -> bf16 convert (all 5 tensors, 1 launch) -----
__global__ void cvt5_kernel(const float* __restrict__ x, const float* __restrict__ z,
                            const float* __restrict__ Wq, const float* __restrict__ Wkv,
                            const float* __restrict__ Wo,
                            u16* __restrict__ xb, u16* __restrict__ zb,
                            u16* __restrict__ wqb, u16* __restrict__ wkvb,
                            u16* __restrict__ wob) {
  const int X4 = 1048576, Z4 = 524288, W4 = 262144;
  const int total = X4 + Z4 + 3 * W4;
  int i = blockIdx.x * blockDim.x + threadIdx.x;
  const int stride = gridDim.x * blockDim.x;
  for (; i < total; i += stride) {
    const float* src; u16* dst; int j = i;
    if (j < X4)              { src = x;   dst = xb; }
    else if ((j -= X4) < Z4) { src = z;   dst = zb; }
    else if ((j -= Z4) < W4) { src = Wq;  dst = wqb; }
    else if ((j -= W4) < W4) { src = Wkv; dst = wkvb; }
    else       { j -= W4;      src = Wo;  dst = wob; }
    float4 v = ((const float4*)src)[j];
    bf16x4 o;
    o[0] = (short)f2bf(v.x); o[1] = (short)f2bf(v.y);
    o[2] = (short)f2bf(v.z); o[3] = (short)f2bf(v.w);
    ((bf16x4*)dst)[j] = o;
  }
}

// ---------- C = scale * A(MxK) @ B(NxK)^T, 128xBN tile, BK=64 --------------
// Staging: chunk c of row r sourced from global chunk c^(r&7) (pre-swizzled
// source, linear LDS). Read: chunk (ks*4+lg) of row lq at slot (ks*4+lg)^(lq&7).
template <int BN, typename CT>
__device__ __forceinline__ void gemm64_body(const u16* __restrict__ A,
                                            const u16* __restrict__ B,
                                            CT* __restrict__ C,
                                            int N, int K, float scale,
                                            int tm, int tn, u16* As, u16* Bs) {
  constexpr int NB = BN / 32;
  const int tid = threadIdx.x;
  const int wid = tid >> 6;
  const int lane = tid & 63;
  const int lg = lane >> 4, lq = lane & 15;
  const int wr = wid >> 1, wc = wid & 1;

  f32x4 acc[4][NB];
#pragma unroll
  for (int m = 0; m < 4; m++)
#pragma unroll
    for (int n = 0; n < NB; n++)
#pragma unroll
      for (int e = 0; e < 4; e++) acc[m][n][e] = 0.f;

  const int r0 = tid >> 3;                 // 0..31
  const int c0 = tid & 7;                  // chunk 0..7
  const int sc = (c0 ^ (r0 & 7)) * 8;      // pre-swizzled source column
  const u16* gA = A + (size_t)(tm * 128 + r0) * K + sc;
  const u16* gB = B + (size_t)(tn * BN + r0) * K + sc;
  u16* lA = As + wid * 512;                // linear LDS dest (512 u16/wave)
  u16* lB = Bs + wid * 512;

  for (int k0 = 0; k0 < K; k0 += 64) {
    __syncthreads();
#pragma unroll
    for (int i = 0; i < 4; i++)            // A: 128 rows = 4 blocks of 32
      gload_lds16(gA + k0 + (size_t)(32 * i) * K, lA + i * 2048);
#pragma unroll
    for (int i = 0; i < NB; i++)           // B: BN rows = NB blocks of 32
      gload_lds16(gB + k0 + (size_t)(32 * i) * K, lB + i * 2048);
    __syncthreads();

#pragma unroll
    for (int ks = 0; ks < 2; ks++) {
      const int slot = ((ks * 4 + lg) ^ (lq & 7)) * 8;
      bf16x8 af[4], bfr[NB];
#pragma unroll
      for (int m = 0; m < 4; m++)
        af[m] = *(const bf16x8*)(As + (wr * 64 + m * 16 + lq) * 64 + slot);
#pragma unroll
      for (int n = 0; n < NB; n++)
        bfr[n] = *(const bf16x8*)(Bs + (wc * (BN / 2) + n * 16 + lq) * 64 + slot);
#pragma unroll
      for (int m = 0; m < 4; m++)
#pragma unroll
        for (int n = 0; n < NB; n++)
          acc[m][n] = __builtin_amdgcn_mfma_f32_16x16x32_bf16(af[m], bfr[n], acc[m][n], 0, 0, 0);
    }
  }

#pragma unroll
  for (int m = 0; m < 4; m++) {
    const int row = tm * 128 + wr * 64 + m * 16 + lg * 4;
#pragma unroll
    for (int i = 0; i < 4; i++) {
      CT* cp = C + (size_t)(row + i) * N + tn * BN + wc * (BN / 2) + lq;
#pragma unroll
      for (int n = 0; n < NB; n++) {
        float v = acc[m][n][i] * scale;
        if constexpr (sizeof(CT) == 2) cp[n * 16] = (CT)f2bf(v);
        else                            cp[n * 16] = (CT)v;
      }
    }
  }
}

// ---------------- fused Q/K/VT projection GEMMs (768 blocks, XCD-chunked) ---
__global__ __launch_bounds__(256, 3) void qkv_gemm(const u16* __restrict__ xb,
                                                   const u16* __restrict__ zb,
                                                   const u16* __restrict__ Wqb,
                                                   const u16* __restrict__ Wkvb,
                                                   u16* __restrict__ Qb,
                                                   u16* __restrict__ Kb,
                                                   u16* __restrict__ VTb) {
  __shared__ __align__(16) u16 As[128 * 64];
  __shared__ __align__(16) u16 Bs[128 * 64];
  // XCD-chunked: each XCD gets 96 consecutive logical g's (A-panels stay local)
  const int bi = blockIdx.x;
  int g = (bi & 7) * 96 + (bi >> 3);
  if (g < 256) {
    // Q = (0.125*log2e) * x @ Wq^T   [4096 x 1024]
    gemm64_body<128, u16>(xb, Wqb, Qb, 1024, 1024, QSCALE, g >> 3, g & 7, As, Bs);
  } else if (g < 512) {
    g -= 256;  // K = z @ Wk^T   [4096 x 1024]
    gemm64_body<128, u16>(zb, Wkvb, Kb, 1024, 512, 1.f, g >> 3, g & 7, As, Bs);
  } else {
    g -= 512;  // VT = Wv @ z^T  [1024 x 4096]
    gemm64_body<128, u16>(Wkvb + 1024 * 512, zb, VTb, 4096, 512, 1.f, g >> 5, g & 31, As, Bs);
  }
}

// ---------------- split-KV combine (streaming, R8-proven) -------------------
__global__ __launch_bounds__(256) void combine_kernel(const u16* __restrict__ OP,
                                                      const float2* __restrict__ ml,
                                                      u16* __restrict__ Ob) {
  const int i = blockIdx.x * 256 + threadIdx.x;   // 0..524287 (8-elem chunks)
  const int grow = i >> 7;
  const int h = (i >> 3) & 15;
  const float2 a0 = ml[grow * 16 + h];
  const float2 a1 = ml[4096 * 16 + grow * 16 + h];
  const float M = fmaxf(a0.x, a1.x);
  float w0 = a0.y * fast_exp2(a0.x - M);
  float w1 = a1.y * fast_exp2(a1.x - M);
  const float inv = 1.f / (w0 + w1);
  w0 *= inv; w1 *= inv;
  const bf16x8 p0 = ((const bf16x8*)OP)[i];
  const bf16x8 p1 = ((const bf16x8*)(OP + (size_t)4096 * 1024))[i];
  bf16x8 o;
#pragma unroll
  for (int e = 0; e < 8; e++) {
    union { uint32_t u; float f; } f0, f1;
    f0.u = ((uint32_t)(u16)p0[e]) << 16;
    f1.u = ((uint32_t)(u16)p1[e]) << 16;
    o[e] = (short)f2bf(w0 * f0.f + w1 * f1.f);
  }
  ((bf16x8*)Ob)[i] = o;
}

// ---------------- O-GEMM: out = O @ Wo^T, fp32 out, 128x64, BK=64 ----------
__global__ __launch_bounds__(256) void o_gemm(const u16* __restrict__ Ob,
                                              const u16* __restrict__ Wob,
                                              float* __restrict__ out) {
  __shared__ __align__(16) u16 As[128 * 64];
  __shared__ __align__(16) u16 Bs[64 * 64];
  // XCD-chunked 1D decode: XCD x handles tm in [4x, 4x+4), all 16 tn
  const int bi = blockIdx.x;              // 0..511
  const int xcd = bi & 7, j = bi >> 3;    // j 0..63
  const int tm = xcd * 4 + (j >> 4);
  const int tn = j & 15;
  gemm64_body<64, float>(Ob, Wob, out, 1024, 1024, 1.f, tm, tn, As, Bs);
}

// ---------------- flash attention, split-KV x2 (R11, proven 58.4 µs) --------
__global__ __launch_bounds__(256, 4) void attn_kernel(const u16* __restrict__ Q,
                                                      const u16* __restrict__ K,
                                                      const u16* __restrict__ VT,
                                                      u16* __restrict__ OP,
                                                      float2* __restrict__ ml) {
  // LDS bytes: K0@0, K1@8192, V0@16384, V1@24576
  __shared__ __align__(16) u16 LDS[16384];

  const int tid = threadIdx.x;
  const int wid = tid >> 6;
  const int lane = tid & 63;
  const int l31 = lane & 31;
  const int hi = lane >> 5;

  // XCD-bijective decode: (xcd | qt | split | bh-group)
  const int bi = blockIdx.x;
  const int xcd = bi & 7, j = bi >> 3;       // j: 0..127
  const int qt = j & 15;
  const int s  = (j >> 4) & 1;
  const int bh = xcd + 8 * (j >> 5);         // 0..31
  const int b = bh >> 4, h = bh & 15;
  const int t0 = s * 16;

  const int q0 = qt * 128 + wid * 32;

  // Q fragments (B-operand): col q = l31, k-elems d = ks*16 + hi*8 .. +7
  bf16x8 qf[4];
  {
    const u16* qp = Q + (size_t)(b * SEQ + q0 + l31) * 1024 + h * 64 + hi * 8;
#pragma unroll
    for (int ks = 0; ks < 4; ks++) qf[ks] = *(const bf16x8*)(qp + ks * 16);
  }

  f32x16 of[2];
#pragma unroll
  for (int d = 0; d < 2; d++)
#pragma unroll
    for (int e = 0; e < 16; e++) of[d][e] = 0.f;
  float m_run = -3.0e38f, l_run = 0.f;

  // tile-invariant per-lane LDS read bases (row l31, swizzled chunk)
  const char* rdB[4];
#pragma unroll
  for (int ks = 0; ks < 4; ks++)
    rdB[ks] = (const char*)LDS + l31 * 128 + ((((2 * ks + hi) ^ (lane & 7))) << 4);

  // staging: wave w stages rows 8w..8w+7 (+32), pre-swizzled source column
  const int r0 = tid >> 3;
  const int srcc = ((tid & 7) ^ (r0 & 7)) << 3;
  const u16* gK = K + (size_t)(b * SEQ + r0) * 1024 + h * 64 + srcc;
  const u16* gV = VT + (size_t)(h * 64 + r0) * 4096 + b * SEQ + srcc;
  u16* lK = LDS + wid * 512;
  u16* lV = LDS + 8192 + wid * 512;

  auto stage = [&](int t, int buf) {
    const u16* sk = gK + (size_t)t * 64 * 1024;
    gload_lds16(sk, lK + buf * 4096);
    gload_lds16(sk + (size_t)32 * 1024, lK + buf * 4096 + 2048);
    const u16* sv = gV + t * 64;
    gload_lds16(sv, lV + buf * 4096);
    gload_lds16(sv + (size_t)32 * 4096, lV + buf * 4096 + 2048);
  };

  auto tile_compute = [&](int buf) {
    const int bo = buf * 8192;   // bytes

    // S^T = K (A) x Q (B): col = q = l31, row = key = kb*32 + (r&3)+8*(r>>2)+4*hi
    f32x16 sacc[2];
#pragma unroll
    for (int kb = 0; kb < 2; kb++)
#pragma unroll
      for (int e = 0; e < 16; e++) sacc[kb][e] = 0.f;
    __builtin_amdgcn_s_setprio(1);
#pragma unroll
    for (int kb = 0; kb < 2; kb++)
#pragma unroll
      for (int ks = 0; ks < 4; ks++) {
        bf16x8 kf = *(const bf16x8*)(rdB[ks] + bo + kb * 4096);
        sacc[kb] = __builtin_amdgcn_mfma_f32_32x32x16_bf16(kf, qf[ks], sacc[kb], 0, 0, 0);
      }
    __builtin_amdgcn_s_setprio(0);

    // tree max over 32 scores (4 parallel chains), then lane^32 pair combine
    float a0 = sacc[0][0], a1 = sacc[0][1], a2 = sacc[0][2], a3 = sacc[0][3];
#pragma unroll
    for (int e = 4; e < 16; e += 4) {
      a0 = fmaxf(a0, sacc[0][e]);     a1 = fmaxf(a1, sacc[0][e + 1]);
      a2 = fmaxf(a2, sacc[0][e + 2]); a3 = fmaxf(a3, sacc[0][e + 3]);
    }
#pragma unroll
    for (int e = 0; e < 16; e += 4) {
      a0 = fmaxf(a0, sacc[1][e]);     a1 = fmaxf(a1, sacc[1][e + 1]);
      a2 = fmaxf(a2, sacc[1][e + 2]); a3 = fmaxf(a3, sacc[1][e + 3]);
    }
    float tmax = fmaxf(fmaxf(a0, a1), fmaxf(a2, a3));
    tmax = fmaxf(tmax, __shfl_xor(tmax, 32));

    if (!__all(tmax <= m_run + DEFER_THR)) {   // defer-max (T13)
      const float m_new = fmaxf(m_run, tmax);
      const float esc = fast_exp2(m_run - m_new);
      l_run *= esc;
#pragma unroll
      for (int r = 0; r < 16; r++) {
        const int qof = (r & 3) + 8 * (r >> 2) + 4 * hi;
        const float e = __shfl(esc, qof);
        of[0][r] *= e;
        of[1][r] *= e;
      }
      m_run = m_new;
    }

    // p = exp2(s - m); psum via 4 parallel chains
    float s0 = 0.f, s1 = 0.f, s2 = 0.f, s3 = 0.f;
#pragma unroll
    for (int kb = 0; kb < 2; kb++)
#pragma unroll
      for (int e = 0; e < 16; e += 4) {
        float p0 = fast_exp2(sacc[kb][e] - m_run);
        float p1 = fast_exp2(sacc[kb][e + 1] - m_run);
        float p2 = fast_exp2(sacc[kb][e + 2] - m_run);
        float p3 = fast_exp2(sacc[kb][e + 3] - m_run);
        sacc[kb][e] = p0; sacc[kb][e + 1] = p1; sacc[kb][e + 2] = p2; sacc[kb][e + 3] = p3;
        s0 += p0; s1 += p1; s2 += p2; s3 += p3;
      }
    l_run += (s0 + s1) + (s2 + s3);

    // pack P to bf16 A-fragments in-register (cvt_pk + shfl_xor exchange)
    bf16x8 pa[4];
#pragma unroll
    for (int kb = 0; kb < 2; kb++) {
      uint32_t c0 = cvtpk(sacc[kb][0],  sacc[kb][1]);
      uint32_t c1 = cvtpk(sacc[kb][2],  sacc[kb][3]);
      uint32_t c2 = cvtpk(sacc[kb][4],  sacc[kb][5]);
      uint32_t c3 = cvtpk(sacc[kb][6],  sacc[kb][7]);
      uint32_t c4 = cvtpk(sacc[kb][8],  sacc[kb][9]);
      uint32_t c5 = cvtpk(sacc[kb][10], sacc[kb][11]);
      uint32_t c6 = cvtpk(sacc[kb][12], sacc[kb][13]);
      uint32_t c7 = cvtpk(sacc[kb][14], sacc[kb][15]);
      swap_pair(c0, c2, hi);
      swap_pair(c1, c3, hi);
      swap_pair(c4, c6, hi);
      swap_pair(c5, c7, hi);
      union { bf16x8 v; uint32_t d[4]; } u0, u1;
      u0.d[0] = c0; u0.d[1] = c1; u0.d[2] = c2; u0.d[3] = c3;
      u1.d[0] = c4; u1.d[1] = c5; u1.d[2] = c6; u1.d[3] = c7;
      pa[2 * kb] = u0.v;
      pa[2 * kb + 1] = u1.v;
    }

    // O += P (A) x V (B): V-frag read inline (short live range, no spill)
    __builtin_amdgcn_s_setprio(1);
#pragma unroll
    for (int ks = 0; ks < 4; ks++)
#pragma unroll
      for (int db = 0; db < 2; db++) {
        bf16x8 vf = *(const bf16x8*)(rdB[ks] + bo + 16384 + db * 4096);
        of[db] = __builtin_amdgcn_mfma_f32_32x32x16_bf16(pa[ks], vf, of[db], 0, 0, 0);
      }
    __builtin_amdgcn_s_setprio(0);
  };

  stage(t0, 0);
  __syncthreads();
#pragma unroll 1
  for (int tt = 0; tt < 16; tt += 2) {
    stage(t0 + tt + 1, 1);
    tile_compute(0);
    __syncthreads();
    if (tt < 14) stage(t0 + tt + 2, 0);
    tile_compute(1);
    __syncthreads();
  }

  // per-split finalize: normalized partial + (m, l)
  const float lsum = l_run + __shfl_xor(l_run, 32);
  const float linv = 1.f / lsum;

  u16* OPs = OP + (size_t)s * 4096 * 1024;
#pragma unroll
  for (int r = 0; r < 16; r++) {
    const int qof = (r & 3) + 8 * (r >> 2) + 4 * hi;
    const float li = __shfl(linv, qof);
    u16* op = OPs + (size_t)(b * SEQ + q0 + qof) * 1024 + h * 64 + l31;
    op[0]  = f2bf(of[0][r] * li);
    op[32] = f2bf(of[1][r] * li);
  }
  if (hi == 0) {
    const int grow = b * SEQ + q0 + l31;
    ml[s * (4096 * 16) + grow * 16 + h] = make_float2(m_run, lsum);
  }
}

// ---------------- launch ----------------
extern "C" void kernel_launch(void* const* d_in, const int* in_sizes, int n_in,
                              void* d_out, int out_size, void* d_ws, size_t ws_size,
                              hipStream_t stream) {
  const float* x   = (const float*)d_in[0];
  const float* z   = (const float*)d_in[1];
  const float* Wq  = (const float*)d_in[2];
  const float* Wkv = (const float*)d_in[3];
  const float* Wo  = (const float*)d_in[4];
  float* out = (float*)d_out;

  char* ws = (char*)d_ws;
  const size_t MB = 1024ull * 1024ull;
  u16* xb   = (u16*)(ws + 0);        // 8 MB  [4096][1024]   (dead after qkv_gemm)
  u16* zb   = (u16*)(ws + 8 * MB);   // 4 MB  [4096][512]    (dead after qkv_gemm)
  u16* Wqb  = (u16*)(ws + 12 * MB);  // 2 MB                 (dead after qkv_gemm)
  u16* Wkvb = (u16*)(ws + 14 * MB);  // 2 MB                 (dead after qkv_gemm)
  u16* Wob  = (u16*)(ws + 16 * MB);  // 2 MB
  u16* Qb   = (u16*)(ws + 18 * MB);  // 8 MB  [4096][1024] (pre-scaled, log2 domain)
  u16* Kb   = (u16*)(ws + 26 * MB);  // 8 MB  [4096][1024]
  u16* VTb  = (u16*)(ws + 34 * MB);  // 8 MB  [1024][4096]
  u16* Ob   = (u16*)(ws + 42 * MB);  // 8 MB  [4096][1024]
  u16* OP   = (u16*)(ws + 0);        // 16 MB [2][4096][1024] partials (reuse xb..Wkvb)
  float2* ml = (float2*)(ws + 50 * MB);  // 1 MB [2][4096][16]

  cvt5_kernel<<<2048, 256, 0, stream>>>(x, z, Wq, Wkv, Wo, xb, zb, Wqb, Wkvb, Wob);

  qkv_gemm<<<768, 256, 0, stream>>>(xb, zb, Wqb, Wkvb, Qb, Kb, VTb);

  attn_kernel<<<1024, 256, 0, stream>>>(Qb, Kb, VTb, OP, ml);

  combine_kernel<<<2048, 256, 0, stream>>>(OP, ml, Ob);

  o_gemm<<<512, 256, 0, stream>>>(Ob, Wob, out);
}